// Round 9
// baseline (318.970 us; speedup 1.0000x reference)
//
#include <hip/hip_runtime.h>
#include <stdint.h>
#include <stddef.h>

// ============================================================================
// MHA block on gfx950, bf16 MFMA pipeline.  B=2,S=2048,D=1024,H=16,hd=64.
// R9 vs R8:
//  - qkv_gemm: REGISTER-DIRECT K-loop.  R4-R8 showed 65-70us / MfmaUtil ~14%
//    invariant under FETCH 21-60MB, BK 32/64, dbuf, stagger -> the binding
//    constraint is the LDS+barrier lockstep itself, not traffic.  New loop:
//    each wave loads its 8 fragments/iter straight to VGPRs (dwordx4, lanes
//    (lm,quad) cover whole 64B lines), 2x-unrolled dbuf prefetch, NO LDS and
//    NO __syncthreads.  L1 absorbs the 2x wave-pair duplication.
//  - flash: qb remap so blocks g and g+256 (same CU under round-robin) get
//    qb + qb' = 15 -> per-CU nkv sum uniform at 34 (was 48..20 imbalance).
//  - stagger dropped (R8: 3x FETCH, no time change).  Swizzle kept (R7).
// MFMA layouts (verified m89/m91/m120):
//   A-frag: A[m=lane&15][k=(lane>>4)*8+j]  (16B/lane contiguous)
//   B-frag: B[k=(lane>>4)*8+j][n=lane&15] == row-major read of B^T tile
//   C/D:    col=lane&15, row=(lane>>4)*4+reg
// ============================================================================

typedef __bf16 bf16x8 __attribute__((ext_vector_type(8)));
typedef float  f32x4  __attribute__((ext_vector_type(4)));

__device__ __forceinline__ unsigned short f2b(float f) {
  union { float f; uint32_t u; } v; v.f = f;
  uint32_t u = v.u;
  return (unsigned short)((u + 0x7FFFu + ((u >> 16) & 1u)) >> 16);  // RNE
}

__device__ __forceinline__ void async16(const void* g, void* l) {
  __builtin_amdgcn_global_load_lds(
      (const __attribute__((address_space(1))) void*)g,
      (__attribute__((address_space(3))) void*)l, 16, 0, 0);
}

// ---------------- all casts in one launch ----------------
__global__ void cast_all_kernel(const float* __restrict__ x,
                                const float* __restrict__ wq, const float* __restrict__ wk,
                                const float* __restrict__ wv, const float* __restrict__ wo,
                                unsigned short* __restrict__ xbf,
                                unsigned short* __restrict__ wqkv,
                                unsigned short* __restrict__ wobf) {
  const int i = blockIdx.x * blockDim.x + threadIdx.x;   // 0 .. 2^21-1
  if (i < (1 << 20)) {
    float4 v = ((const float4*)x)[i];
    ushort4 o;
    o.x = f2b(v.x); o.y = f2b(v.y); o.z = f2b(v.z); o.w = f2b(v.w);
    ((ushort4*)xbf)[i] = o;
  } else {
    const int j = i - (1 << 20);                         // 0 .. 4*2^18-1
    const int sel = j >> 18, k = j & ((1 << 18) - 1);
    const float* src = (sel == 0) ? wq : (sel == 1) ? wk : (sel == 2) ? wv : wo;
    float4 v = ((const float4*)src)[k];
    ushort4 o;
    o.x = f2b(v.x); o.y = f2b(v.y); o.z = f2b(v.z); o.w = f2b(v.w);
    if (sel < 3) ((ushort4*)wqkv)[(size_t)sel * 262144 + k] = o;
    else         ((ushort4*)wobf)[k] = o;
  }
}

// ---------------- fused QKV projection GEMM (+bias, +RoPE on q/k) ----------
// C[4096,3072] = Xbf[4096,1024] @ Wqkv[3072,1024]^T, 128x128 tiles, BK=32.
// Register-direct: no LDS, no barriers; 2x-unrolled dbuf fragment prefetch.
__global__ __launch_bounds__(256) void qkv_gemm_kernel(
    const unsigned short* __restrict__ A,    // x_bf [4096][1024]
    const unsigned short* __restrict__ W,    // wqkv [3072][1024]
    const float* __restrict__ biasq, const float* __restrict__ biask,
    const float* __restrict__ biasv,
    const float* __restrict__ cp, const float* __restrict__ sp,  // [2048][32]
    unsigned short* __restrict__ qo,
    unsigned short* __restrict__ ko,
    unsigned short* __restrict__ vo)
{
  const int tid  = threadIdx.x;
  const int w    = tid >> 6, l = tid & 63;
  const int lm   = l & 15,  quad = l >> 4;
  const int g    = blockIdx.x;               // 0..767
  const int xcd  = g & 7, t = g >> 3;        // t: 0..95
  const int mg   = (xcd >> 1) * 8 + (t & 7);    // 0..31
  const int nblk = (xcd & 1) * 12 + (t >> 3);   // 0..23
  const int m0   = mg * 128;
  const int n0g  = nblk * 128;
  const int wm   = (w >> 1) * 64, wn = (w & 1) * 64;

  const f32x4 fzero = {0.f, 0.f, 0.f, 0.f};
  f32x4 acc[4][4];
#pragma unroll
  for (int i = 0; i < 4; ++i)
#pragma unroll
    for (int j = 0; j < 4; ++j) acc[i][j] = fzero;

  // lane (lm,quad): row base +lm, 8 bf16 at k0+quad*8.  quad 0..3 with same
  // lm cover one full 64B line.  i-th fragment: +i*16 rows (= 16384 shorts).
  const unsigned short* pa = A + (size_t)(m0 + wm + lm) * 1024 + quad * 8;
  const unsigned short* pb = W + (size_t)(n0g + wn + lm) * 1024 + quad * 8;

  bf16x8 a0[4], b0[4], a1[4], b1[4];
#pragma unroll
  for (int i = 0; i < 4; ++i) {
    a0[i] = *(const bf16x8*)(pa + (size_t)i * 16384);
    b0[i] = *(const bf16x8*)(pb + (size_t)i * 16384);
  }

  for (int it = 0; it < 32; it += 2) {
    {  // prefetch it+1 (always valid: it+1 <= 31)
      const int k0 = (it + 1) * 32;
#pragma unroll
      for (int i = 0; i < 4; ++i) {
        a1[i] = *(const bf16x8*)(pa + (size_t)i * 16384 + k0);
        b1[i] = *(const bf16x8*)(pb + (size_t)i * 16384 + k0);
      }
    }
#pragma unroll
    for (int i = 0; i < 4; ++i)
#pragma unroll
      for (int j = 0; j < 4; ++j)
        acc[i][j] = __builtin_amdgcn_mfma_f32_16x16x32_bf16(a0[i], b0[j], acc[i][j], 0, 0, 0);
    if (it + 2 < 32) {  // prefetch it+2
      const int k0 = (it + 2) * 32;
#pragma unroll
      for (int i = 0; i < 4; ++i) {
        a0[i] = *(const bf16x8*)(pa + (size_t)i * 16384 + k0);
        b0[i] = *(const bf16x8*)(pb + (size_t)i * 16384 + k0);
      }
    }
#pragma unroll
    for (int i = 0; i < 4; ++i)
#pragma unroll
      for (int j = 0; j < 4; ++j)
        acc[i][j] = __builtin_amdgcn_mfma_f32_16x16x32_bf16(a1[i], b1[j], acc[i][j], 0, 0, 0);
  }

  const int which = nblk >> 3;               // 0=q 1=k 2=v
  const int n0    = (nblk & 7) * 128;
  const float* bias = (which == 0) ? biasq : (which == 1) ? biask : biasv;
#pragma unroll
  for (int i = 0; i < 4; ++i) {
#pragma unroll
    for (int j = 0; j < 4; ++j) {
      const int n = n0 + wn + j * 16 + lm;
      const float bval = bias[n];
      const int h = n >> 6, d = n & 63;
      float vals[4];
#pragma unroll
      for (int r = 0; r < 4; ++r) {
        const int m = m0 + wm + i * 16 + quad * 4 + r;
        const int srow = m & 2047;
        float val = acc[i][j][r] + bval;
        if (which != 2) {
          const float c  = cp[srow * 32 + (d >> 1)];
          const float sn = sp[srow * 32 + (d >> 1)];
          const float part = __shfl_xor(val, 1, 64);
          val = (d & 1) ? (part * sn + val * c) : (val * c - part * sn);
        }
        vals[r] = val;
      }
      const int mbase = m0 + wm + i * 16 + quad * 4;   // 4 consecutive s
      const int b = mbase >> 11, s0 = mbase & 2047;
      const int bh = (b << 4) + h;
      if (which == 0) {
#pragma unroll
        for (int r = 0; r < 4; ++r)
          qo[((size_t)bh * 2048 + s0 + r) * 64 + d] = f2b(vals[r]);
      } else if (which == 1) {
        // tiled: base = (bh*32 + s>>6)*4096 + ((d>>3)*64 + (s&63))*8 + (d&7)
#pragma unroll
        for (int r = 0; r < 4; ++r) {
          const int s = s0 + r;
          ko[((size_t)bh * 32 + (s >> 6)) * 4096 +
             (size_t)(((d >> 3) * 64 + (s & 63))) * 8 + (d & 7)] = f2b(vals[r]);
        }
      } else {
        // V^T tiled, 4 consecutive s -> one uint2 (8B) store
        uint32_t w0 = (uint32_t)f2b(vals[0]) | ((uint32_t)f2b(vals[1]) << 16);
        uint32_t w1 = (uint32_t)f2b(vals[2]) | ((uint32_t)f2b(vals[3]) << 16);
        uint2 pk; pk.x = w0; pk.y = w1;
        *(uint2*)(vo + ((size_t)bh * 32 + (s0 >> 6)) * 4096 +
                  (size_t)((((s0 & 63) >> 3) * 64 + d)) * 8 + (s0 & 7)) = pk;
      }
    }
  }
}

// ---------------- flash attention ----------------
// grid (bh=32, 16); block 512 thr = 8 waves; wave w owns q-rows w*16..w*16+15.
// S^T = K*Q^T: t in-lane, m = lane&15.  Dbuf K/V tiles.
// qb remap: y<8 -> qb=15-y (heavy first); y>=8 -> qb=y-8.  Blocks g,g+256
// pair to qb+qb'=15 -> per-CU nkv sum = 34 uniform.
__global__ __launch_bounds__(512, 4) void flash_kernel(
    const unsigned short* __restrict__ Q,    // [32][2048][64] row-major
    const unsigned short* __restrict__ K,    // tiled frag-major (see qkv)
    const unsigned short* __restrict__ VT,   // V^T tiled frag-major
    unsigned short* __restrict__ O)          // [2][2048][1024]
{
  constexpr int PSTRIDE = 72;                // Ps row stride (shorts)
  __shared__ unsigned short Ks[2][4096];     // 64x64 tile, chunk L = c*64 + t
  __shared__ unsigned short Vs[2][4096];     // V^T tile, chunk L = ct*64 + d
  __shared__ unsigned short Ps[128 * PSTRIDE];
  const int tid = threadIdx.x;
  const int w = tid >> 6, l = tid & 63, lm = l & 15, quad = l >> 4;
  const int bh = blockIdx.x;
  const int y  = blockIdx.y;
  const int qb = (y < 8) ? (15 - y) : (y - 8);
  const int mrow_g = qb * 128 + w * 16 + lm;         // this lane's softmax row

  // Q fragment to registers: lane reads row (qb*128+w*16+lm), 8 d at quad*8
  const size_t qbase = ((size_t)bh * 2048 + (size_t)qb * 128) * 64;
  bf16x8 aq[2];
#pragma unroll
  for (int kc = 0; kc < 2; ++kc)
    aq[kc] = *(const bf16x8*)(Q + qbase + (size_t)(w * 16 + lm) * 64 + kc * 32 + quad * 8);

  const f32x4 fzero = {0.f, 0.f, 0.f, 0.f};
  f32x4 Oacc[4];
#pragma unroll
  for (int jo = 0; jo < 4; ++jo) Oacc[jo] = fzero;
  float m_i = -1e30f, l_i = 0.f;

  const unsigned short* kb = K  + ((size_t)bh * 32) * 4096 + (size_t)tid * 8;
  const unsigned short* vb = VT + ((size_t)bh * 32) * 4096 + (size_t)tid * 8;
  const size_t dst = (size_t)w * 512;

  // prefetch kt=0 into buffer 0
  async16(kb, Ks[0] + dst);
  async16(vb, Vs[0] + dst);

  const int nkv = 2 * qb + 2;
  for (int kt = 0; kt < nkv; ++kt) {
    __syncthreads();                 // drains tile-kt loads; buf^1 readers done
    const int cur = kt & 1;
    if (kt + 1 < nkv) {
      const size_t off = (size_t)(kt + 1) * 4096;
      async16(kb + off, Ks[cur ^ 1] + dst);
      async16(vb + off, Vs[cur ^ 1] + dst);
    }

    // S^T = K * Q^T : Sc[tb] holds t = tb*16+quad*4+r (rows), m = lm (col)
    f32x4 Sc[4];
#pragma unroll
    for (int tb = 0; tb < 4; ++tb) Sc[tb] = fzero;
#pragma unroll
    for (int kc = 0; kc < 2; ++kc) {
      bf16x8 ak[4];
#pragma unroll
      for (int tb = 0; tb < 4; ++tb)
        ak[tb] = *(const bf16x8*)(Ks[cur] + (size_t)(((kc * 4 + quad) * 64 + tb * 16 + lm)) * 8);
#pragma unroll
      for (int tb = 0; tb < 4; ++tb)
        Sc[tb] = __builtin_amdgcn_mfma_f32_16x16x32_bf16(ak[tb], aq[kc], Sc[tb], 0, 0, 0);
    }

    // scale + causal mask.  Mask needed iff tile's max t (kt*64+63) exceeds
    // this wave's MIN row (qb*128 + w*16).
    const bool needmask = (kt * 64 + 63 > qb * 128 + w * 16);
    const int  mrel = mrow_g - kt * 64;      // mask t-index > mrel
    float mx = -1e30f;
#pragma unroll
    for (int tb = 0; tb < 4; ++tb) {
#pragma unroll
      for (int r = 0; r < 4; ++r) {
        float s = Sc[tb][r] * 0.125f;        // 1/sqrt(64)
        if (needmask && (tb * 16 + quad * 4 + r > mrel)) s = -1e30f;
        Sc[tb][r] = s;
        mx = fmaxf(mx, s);
      }
    }
    mx = fmaxf(mx, __shfl_xor(mx, 16, 64));
    mx = fmaxf(mx, __shfl_xor(mx, 32, 64));
    const float mnew  = fmaxf(m_i, mx);
    const float alpha = __expf(m_i - mnew);
    m_i = mnew;

    // exp, pack 4 consecutive t -> b64 write into Ps[m][t]
    float ps = 0.f;
#pragma unroll
    for (int tb = 0; tb < 4; ++tb) {
      float p0 = __expf(Sc[tb][0] - mnew), p1 = __expf(Sc[tb][1] - mnew);
      float p2 = __expf(Sc[tb][2] - mnew), p3 = __expf(Sc[tb][3] - mnew);
      ps += (p0 + p1) + (p2 + p3);
      uint2 pk;
      pk.x = (uint32_t)f2b(p0) | ((uint32_t)f2b(p1) << 16);
      pk.y = (uint32_t)f2b(p2) | ((uint32_t)f2b(p3) << 16);
      *(uint2*)(Ps + (size_t)(w * 16 + lm) * PSTRIDE + tb * 16 + quad * 4) = pk;
    }
    ps += __shfl_xor(ps, 16, 64);
    ps += __shfl_xor(ps, 32, 64);
    l_i = l_i * alpha + ps;

    // rescale Oacc: alpha lives per m=lm; O rows are quad*4+r -> shuffle
    float af4[4];
#pragma unroll
    for (int r = 0; r < 4; ++r) af4[r] = __shfl(alpha, quad * 4 + r, 64);
#pragma unroll
    for (int jo = 0; jo < 4; ++jo)
#pragma unroll
      for (int r = 0; r < 4; ++r) Oacc[jo][r] *= af4[r];

    // O += P V  (wave-private Ps rows; lgkmcnt orders write->read in-wave)
#pragma unroll
    for (int kc = 0; kc < 2; ++kc) {
      bf16x8 ap = *(const bf16x8*)(Ps + (size_t)(w * 16 + lm) * PSTRIDE + kc * 32 + quad * 8);
      bf16x8 bv[4];
#pragma unroll
      for (int jo = 0; jo < 4; ++jo)
        bv[jo] = *(const bf16x8*)(Vs[cur] + (size_t)(((kc * 4 + quad) * 64 + jo * 16 + lm)) * 8);
#pragma unroll
      for (int jo = 0; jo < 4; ++jo)
        Oacc[jo] = __builtin_amdgcn_mfma_f32_16x16x32_bf16(ap, bv[jo], Oacc[jo], 0, 0, 0);
    }
  }

  // epilogue: normalize, write o_bf (b, s, h*64+d)
  float lf[4];
#pragma unroll
  for (int r = 0; r < 4; ++r) lf[r] = 1.0f / __shfl(l_i, quad * 4 + r, 64);
  const int b = bh >> 4, h = bh & 15;
#pragma unroll
  for (int jo = 0; jo < 4; ++jo)
#pragma unroll
    for (int r = 0; r < 4; ++r) {
      const int s   = qb * 128 + w * 16 + quad * 4 + r;
      const int col = h * 64 + jo * 16 + lm;
      O[((size_t)b * 2048 + s) * 1024 + col] = f2b(Oacc[jo][r] * lf[r]);
    }
}

// ---------------- output projection GEMM ----------------
// out[4096,1024] = Obf[4096,1024] @ Wo[1024,1024]^T + bias (fp32 out).
// 64x128 tiles, BK=32 dbuf; XCD rectangle 16m x 4n (3MB set).
__global__ __launch_bounds__(256) void oproj_gemm_kernel(
    const unsigned short* __restrict__ A,    // o_bf [4096][1024]
    const unsigned short* __restrict__ W,    // wo_bf [1024][1024]
    const float* __restrict__ bias,
    float* __restrict__ out)
{
  __shared__ unsigned short As[2][64 * 32];  // 4 KB x2
  __shared__ unsigned short Bs[2][128 * 32]; // 8 KB x2
  const int tid = threadIdx.x;
  const int w = tid >> 6, l = tid & 63;
  const int lm = l & 15, quad = l >> 4;
  const int g = blockIdx.x;                  // 0..511
  const int xcd = g & 7, t = g >> 3;         // t: 0..63
  const int m0 = ((xcd >> 1) * 16 + (t & 15)) * 64;
  const int n0 = ((xcd & 1) * 4 + (t >> 4)) * 128;

  const f32x4 fzero = {0.f, 0.f, 0.f, 0.f};
  f32x4 acc[4][2];
#pragma unroll
  for (int i = 0; i < 4; ++i)
#pragma unroll
    for (int j = 0; j < 2; ++j) acc[i][j] = fzero;

  const int rowS = w * 16 + lm;
  const unsigned short* ga  = A + (size_t)(m0 + rowS) * 1024 + quad * 8;
  const unsigned short* gb0 = W + (size_t)(n0 + rowS) * 1024 + quad * 8;
  const unsigned short* gb1 = W + (size_t)(n0 + rowS + 64) * 1024 + quad * 8;
  const size_t da = (size_t)(w * 64) * 8;
  const size_t db0 = da, db1 = (size_t)((w + 4) * 64) * 8;

  async16(ga,  As[0] + da);
  async16(gb0, Bs[0] + db0);
  async16(gb1, Bs[0] + db1);

  for (int it = 0; it < 32; ++it) {
    __syncthreads();
    const int cur = it & 1;
    if (it < 31) {
      const int k0 = (it + 1) * 32;
      async16(ga + k0,  As[cur ^ 1] + da);
      async16(gb0 + k0, Bs[cur ^ 1] + db0);
      async16(gb1 + k0, Bs[cur ^ 1] + db1);
    }
    bf16x8 af[4], bfc[2];
#pragma unroll
    for (int i = 0; i < 4; ++i)
      af[i] = *(const bf16x8*)(As[cur] + (size_t)((i * 64 + l)) * 8);
#pragma unroll
    for (int j = 0; j < 2; ++j)
      bfc[j] = *(const bf16x8*)(Bs[cur] + (size_t)(((w * 2 + j) * 64 + l)) * 8);
#pragma unroll
    for (int i = 0; i < 4; ++i)
#pragma unroll
      for (int j = 0; j < 2; ++j)
        acc[i][j] = __builtin_amdgcn_mfma_f32_16x16x32_bf16(af[i], bfc[j], acc[i][j], 0, 0, 0);
  }

#pragma unroll
  for (int i = 0; i < 4; ++i) {
#pragma unroll
    for (int j = 0; j < 2; ++j) {
      const int n = n0 + w * 32 + j * 16 + lm;
      const float bval = bias[n];
#pragma unroll
      for (int r = 0; r < 4; ++r) {
        const int m = m0 + i * 16 + quad * 4 + r;
        out[(size_t)m * 1024 + n] = acc[i][j][r] + bval;
      }
    }
  }
}

// ---------------- host launch ----------------
extern "C" void kernel_launch(void* const* d_in, const int* in_sizes, int n_in,
                              void* d_out, int out_size, void* d_ws, size_t ws_size,
                              hipStream_t stream) {
  (void)in_sizes; (void)n_in; (void)out_size; (void)ws_size;
  const float* x  = (const float*)d_in[0];
  const float* cp = (const float*)d_in[1];
  const float* sp = (const float*)d_in[2];
  const float* wq = (const float*)d_in[3];
  const float* bq = (const float*)d_in[4];
  const float* wk = (const float*)d_in[5];
  const float* bk = (const float*)d_in[6];
  const float* wv = (const float*)d_in[7];
  const float* bv = (const float*)d_in[8];
  const float* wo = (const float*)d_in[9];
  const float* bo = (const float*)d_in[10];
  float* out = (float*)d_out;

  unsigned short* xbf  = (unsigned short*)d_ws;          // 4M shorts
  unsigned short* wqkv = xbf  + (size_t)4 * 1024 * 1024; // 3M
  unsigned short* wobf = wqkv + (size_t)3 * 1024 * 1024; // 1M
  unsigned short* qbf  = wobf + (size_t)1 * 1024 * 1024; // 4M (bh,s,d)
  unsigned short* kbf  = qbf  + (size_t)4 * 1024 * 1024; // 4M (tiled frag-major)
  unsigned short* vbf  = kbf  + (size_t)4 * 1024 * 1024; // 4M (V^T tiled)
  unsigned short* obf  = vbf  + (size_t)4 * 1024 * 1024; // 4M (b,s,h*64+d)

  hipLaunchKernelGGL(cast_all_kernel, dim3(8192), dim3(256), 0, stream,
                     x, wq, wk, wv, wo, xbf, wqkv, wobf);

  hipLaunchKernelGGL(qkv_gemm_kernel, dim3(768), dim3(256), 0, stream,
                     xbf, wqkv, bq, bk, bv, cp, sp, qbf, kbf, vbf);
  hipLaunchKernelGGL(flash_kernel, dim3(32, 16), dim3(512), 0, stream,
                     qbf, kbf, vbf, obf);
  hipLaunchKernelGGL(oproj_gemm_kernel, dim3(512), dim3(256), 0, stream,
                     obf, wobf, bo, out);
}

// Round 10
// 237.010 us; speedup vs baseline: 1.3458x; 1.3458x over previous
//
#include <hip/hip_runtime.h>
#include <stdint.h>
#include <stddef.h>

// ============================================================================
// MHA block on gfx950, bf16 MFMA pipeline.  B=2,S=2048,D=1024,H=16,hd=64.
// R10: consolidation to best-known-per-stage after R9's falsification round.
//  - qkv_gemm: R7 config (LDS dbuf single-barrier, BK=32, XCD rectangle
//    swizzle, NO stagger).  R4-R9 established ~65us is this structure's
//    plateau at shape (4096x3072x1024), matching the verified m102 curve;
//    register-direct (R9) regressed 2.2x -> LDS staging + barrier is load-
//    latency amortization, not overhead.
//  - flash: R9 qb-pairing kept (blocks g,g+256 sum nkv to 34 -> uniform CU
//    load).  Isolated measurement this round.
//  - oproj (64x128 BK32 dbuf + swizzle), cast_all: unchanged from R8.
// MFMA layouts (verified m89/m91/m120):
//   A-frag: A[m=lane&15][k=(lane>>4)*8+j]  (16B/lane contiguous)
//   B-frag: B[k=(lane>>4)*8+j][n=lane&15] == row-major read of B^T tile
//   C/D:    col=lane&15, row=(lane>>4)*4+reg
// ============================================================================

typedef __bf16 bf16x8 __attribute__((ext_vector_type(8)));
typedef float  f32x4  __attribute__((ext_vector_type(4)));

__device__ __forceinline__ unsigned short f2b(float f) {
  union { float f; uint32_t u; } v; v.f = f;
  uint32_t u = v.u;
  return (unsigned short)((u + 0x7FFFu + ((u >> 16) & 1u)) >> 16);  // RNE
}

__device__ __forceinline__ void async16(const void* g, void* l) {
  __builtin_amdgcn_global_load_lds(
      (const __attribute__((address_space(1))) void*)g,
      (__attribute__((address_space(3))) void*)l, 16, 0, 0);
}

// ---------------- all casts in one launch ----------------
__global__ void cast_all_kernel(const float* __restrict__ x,
                                const float* __restrict__ wq, const float* __restrict__ wk,
                                const float* __restrict__ wv, const float* __restrict__ wo,
                                unsigned short* __restrict__ xbf,
                                unsigned short* __restrict__ wqkv,
                                unsigned short* __restrict__ wobf) {
  const int i = blockIdx.x * blockDim.x + threadIdx.x;   // 0 .. 2^21-1
  if (i < (1 << 20)) {
    float4 v = ((const float4*)x)[i];
    ushort4 o;
    o.x = f2b(v.x); o.y = f2b(v.y); o.z = f2b(v.z); o.w = f2b(v.w);
    ((ushort4*)xbf)[i] = o;
  } else {
    const int j = i - (1 << 20);                         // 0 .. 4*2^18-1
    const int sel = j >> 18, k = j & ((1 << 18) - 1);
    const float* src = (sel == 0) ? wq : (sel == 1) ? wk : (sel == 2) ? wv : wo;
    float4 v = ((const float4*)src)[k];
    ushort4 o;
    o.x = f2b(v.x); o.y = f2b(v.y); o.z = f2b(v.z); o.w = f2b(v.w);
    if (sel < 3) ((ushort4*)wqkv)[(size_t)sel * 262144 + k] = o;
    else         ((ushort4*)wobf)[k] = o;
  }
}

// ---------------- fused QKV projection GEMM (+bias, +RoPE on q/k) ----------
// C[4096,3072] = Xbf[4096,1024] @ Wqkv[3072,1024]^T, 128x128 tiles, BK=32,
// dbuf single-barrier pipeline, XCD-rectangle swizzle (8m x 12n per XCD).
__global__ __launch_bounds__(256) void qkv_gemm_kernel(
    const unsigned short* __restrict__ A,    // x_bf [4096][1024]
    const unsigned short* __restrict__ W,    // wqkv [3072][1024]
    const float* __restrict__ biasq, const float* __restrict__ biask,
    const float* __restrict__ biasv,
    const float* __restrict__ cp, const float* __restrict__ sp,  // [2048][32]
    unsigned short* __restrict__ qo,
    unsigned short* __restrict__ ko,
    unsigned short* __restrict__ vo)
{
  __shared__ unsigned short As[2][128 * 32];
  __shared__ unsigned short Bs[2][128 * 32];
  const int tid  = threadIdx.x;
  const int w    = tid >> 6, l = tid & 63;
  const int lm   = l & 15,  quad = l >> 4;
  const int g    = blockIdx.x;               // 0..767
  const int xcd  = g & 7, t = g >> 3;        // t: 0..95
  const int mg   = (xcd >> 1) * 8 + (t & 7);    // 0..31
  const int nblk = (xcd & 1) * 12 + (t >> 3);   // 0..23
  const int m0   = mg * 128;
  const int n0g  = nblk * 128;
  const int wm   = (w >> 1) * 64, wn = (w & 1) * 64;

  const f32x4 fzero = {0.f, 0.f, 0.f, 0.f};
  f32x4 acc[4][4];
#pragma unroll
  for (int i = 0; i < 4; ++i)
#pragma unroll
    for (int j = 0; j < 4; ++j) acc[i][j] = fzero;

  const int rowS = w * 16 + lm;
  const unsigned short* ga0 = A + (size_t)(m0 + rowS) * 1024 + quad * 8;
  const unsigned short* ga1 = A + (size_t)(m0 + rowS + 64) * 1024 + quad * 8;
  const unsigned short* gb0 = W + (size_t)(n0g + rowS) * 1024 + quad * 8;
  const unsigned short* gb1 = W + (size_t)(n0g + rowS + 64) * 1024 + quad * 8;
  const size_t d0 = (size_t)(w * 64) * 8, d1 = (size_t)(w * 64 + 256) * 8;

  // prefetch tile 0 into buffer 0
  async16(ga0, As[0] + d0);
  async16(ga1, As[0] + d1);
  async16(gb0, Bs[0] + d0);
  async16(gb1, Bs[0] + d1);

  for (int it = 0; it < 32; ++it) {
    __syncthreads();                 // drains tile-it loads; buf^1 readers done
    const int cur = it & 1;
    if (it < 31) {
      const int k0 = (it + 1) * 32;
      async16(ga0 + k0, As[cur ^ 1] + d0);
      async16(ga1 + k0, As[cur ^ 1] + d1);
      async16(gb0 + k0, Bs[cur ^ 1] + d0);
      async16(gb1 + k0, Bs[cur ^ 1] + d1);
    }
    bf16x8 af[4], bfc[4];
#pragma unroll
    for (int i = 0; i < 4; ++i)
      af[i] = *(const bf16x8*)(As[cur] + (size_t)((((w >> 1) * 4 + i) * 64 + l)) * 8);
#pragma unroll
    for (int j = 0; j < 4; ++j)
      bfc[j] = *(const bf16x8*)(Bs[cur] + (size_t)((((w & 1) * 4 + j) * 64 + l)) * 8);
#pragma unroll
    for (int i = 0; i < 4; ++i)
#pragma unroll
      for (int j = 0; j < 4; ++j)
        acc[i][j] = __builtin_amdgcn_mfma_f32_16x16x32_bf16(af[i], bfc[j], acc[i][j], 0, 0, 0);
  }

  const int which = nblk >> 3;               // 0=q 1=k 2=v
  const int n0    = (nblk & 7) * 128;
  const float* bias = (which == 0) ? biasq : (which == 1) ? biask : biasv;
#pragma unroll
  for (int i = 0; i < 4; ++i) {
#pragma unroll
    for (int j = 0; j < 4; ++j) {
      const int n = n0 + wn + j * 16 + lm;
      const float bval = bias[n];
      const int h = n >> 6, d = n & 63;
      float vals[4];
#pragma unroll
      for (int r = 0; r < 4; ++r) {
        const int m = m0 + wm + i * 16 + quad * 4 + r;
        const int srow = m & 2047;
        float val = acc[i][j][r] + bval;
        if (which != 2) {
          const float c  = cp[srow * 32 + (d >> 1)];
          const float sn = sp[srow * 32 + (d >> 1)];
          const float part = __shfl_xor(val, 1, 64);
          val = (d & 1) ? (part * sn + val * c) : (val * c - part * sn);
        }
        vals[r] = val;
      }
      const int mbase = m0 + wm + i * 16 + quad * 4;   // 4 consecutive s
      const int b = mbase >> 11, s0 = mbase & 2047;
      const int bh = (b << 4) + h;
      if (which == 0) {
#pragma unroll
        for (int r = 0; r < 4; ++r)
          qo[((size_t)bh * 2048 + s0 + r) * 64 + d] = f2b(vals[r]);
      } else if (which == 1) {
        // tiled: base = (bh*32 + s>>6)*4096 + ((d>>3)*64 + (s&63))*8 + (d&7)
#pragma unroll
        for (int r = 0; r < 4; ++r) {
          const int s = s0 + r;
          ko[((size_t)bh * 32 + (s >> 6)) * 4096 +
             (size_t)(((d >> 3) * 64 + (s & 63))) * 8 + (d & 7)] = f2b(vals[r]);
        }
      } else {
        // V^T tiled, 4 consecutive s -> one uint2 (8B) store
        uint32_t w0 = (uint32_t)f2b(vals[0]) | ((uint32_t)f2b(vals[1]) << 16);
        uint32_t w1 = (uint32_t)f2b(vals[2]) | ((uint32_t)f2b(vals[3]) << 16);
        uint2 pk; pk.x = w0; pk.y = w1;
        *(uint2*)(vo + ((size_t)bh * 32 + (s0 >> 6)) * 4096 +
                  (size_t)((((s0 & 63) >> 3) * 64 + d)) * 8 + (s0 & 7)) = pk;
      }
    }
  }
}

// ---------------- flash attention ----------------
// grid (bh=32, 16); block 512 thr = 8 waves; wave w owns q-rows w*16..w*16+15.
// S^T = K*Q^T: t in-lane, m = lane&15.  Dbuf K/V tiles.
// qb remap: y<8 -> qb=15-y (heavy first); y>=8 -> qb=y-8.  Blocks g,g+256
// pair to qb+qb'=15 -> per-CU nkv sum = 34 uniform.
__global__ __launch_bounds__(512, 4) void flash_kernel(
    const unsigned short* __restrict__ Q,    // [32][2048][64] row-major
    const unsigned short* __restrict__ K,    // tiled frag-major (see qkv)
    const unsigned short* __restrict__ VT,   // V^T tiled frag-major
    unsigned short* __restrict__ O)          // [2][2048][1024]
{
  constexpr int PSTRIDE = 72;                // Ps row stride (shorts)
  __shared__ unsigned short Ks[2][4096];     // 64x64 tile, chunk L = c*64 + t
  __shared__ unsigned short Vs[2][4096];     // V^T tile, chunk L = ct*64 + d
  __shared__ unsigned short Ps[128 * PSTRIDE];
  const int tid = threadIdx.x;
  const int w = tid >> 6, l = tid & 63, lm = l & 15, quad = l >> 4;
  const int bh = blockIdx.x;
  const int y  = blockIdx.y;
  const int qb = (y < 8) ? (15 - y) : (y - 8);
  const int mrow_g = qb * 128 + w * 16 + lm;         // this lane's softmax row

  // Q fragment to registers: lane reads row (qb*128+w*16+lm), 8 d at quad*8
  const size_t qbase = ((size_t)bh * 2048 + (size_t)qb * 128) * 64;
  bf16x8 aq[2];
#pragma unroll
  for (int kc = 0; kc < 2; ++kc)
    aq[kc] = *(const bf16x8*)(Q + qbase + (size_t)(w * 16 + lm) * 64 + kc * 32 + quad * 8);

  const f32x4 fzero = {0.f, 0.f, 0.f, 0.f};
  f32x4 Oacc[4];
#pragma unroll
  for (int jo = 0; jo < 4; ++jo) Oacc[jo] = fzero;
  float m_i = -1e30f, l_i = 0.f;

  const unsigned short* kb = K  + ((size_t)bh * 32) * 4096 + (size_t)tid * 8;
  const unsigned short* vb = VT + ((size_t)bh * 32) * 4096 + (size_t)tid * 8;
  const size_t dst = (size_t)w * 512;

  // prefetch kt=0 into buffer 0
  async16(kb, Ks[0] + dst);
  async16(vb, Vs[0] + dst);

  const int nkv = 2 * qb + 2;
  for (int kt = 0; kt < nkv; ++kt) {
    __syncthreads();                 // drains tile-kt loads; buf^1 readers done
    const int cur = kt & 1;
    if (kt + 1 < nkv) {
      const size_t off = (size_t)(kt + 1) * 4096;
      async16(kb + off, Ks[cur ^ 1] + dst);
      async16(vb + off, Vs[cur ^ 1] + dst);
    }

    // S^T = K * Q^T : Sc[tb] holds t = tb*16+quad*4+r (rows), m = lm (col)
    f32x4 Sc[4];
#pragma unroll
    for (int tb = 0; tb < 4; ++tb) Sc[tb] = fzero;
#pragma unroll
    for (int kc = 0; kc < 2; ++kc) {
      bf16x8 ak[4];
#pragma unroll
      for (int tb = 0; tb < 4; ++tb)
        ak[tb] = *(const bf16x8*)(Ks[cur] + (size_t)(((kc * 4 + quad) * 64 + tb * 16 + lm)) * 8);
#pragma unroll
      for (int tb = 0; tb < 4; ++tb)
        Sc[tb] = __builtin_amdgcn_mfma_f32_16x16x32_bf16(ak[tb], aq[kc], Sc[tb], 0, 0, 0);
    }

    // scale + causal mask.  Mask needed iff tile's max t (kt*64+63) exceeds
    // this wave's MIN row (qb*128 + w*16).
    const bool needmask = (kt * 64 + 63 > qb * 128 + w * 16);
    const int  mrel = mrow_g - kt * 64;      // mask t-index > mrel
    float mx = -1e30f;
#pragma unroll
    for (int tb = 0; tb < 4; ++tb) {
#pragma unroll
      for (int r = 0; r < 4; ++r) {
        float s = Sc[tb][r] * 0.125f;        // 1/sqrt(64)
        if (needmask && (tb * 16 + quad * 4 + r > mrel)) s = -1e30f;
        Sc[tb][r] = s;
        mx = fmaxf(mx, s);
      }
    }
    mx = fmaxf(mx, __shfl_xor(mx, 16, 64));
    mx = fmaxf(mx, __shfl_xor(mx, 32, 64));
    const float mnew  = fmaxf(m_i, mx);
    const float alpha = __expf(m_i - mnew);
    m_i = mnew;

    // exp, pack 4 consecutive t -> b64 write into Ps[m][t]
    float ps = 0.f;
#pragma unroll
    for (int tb = 0; tb < 4; ++tb) {
      float p0 = __expf(Sc[tb][0] - mnew), p1 = __expf(Sc[tb][1] - mnew);
      float p2 = __expf(Sc[tb][2] - mnew), p3 = __expf(Sc[tb][3] - mnew);
      ps += (p0 + p1) + (p2 + p3);
      uint2 pk;
      pk.x = (uint32_t)f2b(p0) | ((uint32_t)f2b(p1) << 16);
      pk.y = (uint32_t)f2b(p2) | ((uint32_t)f2b(p3) << 16);
      *(uint2*)(Ps + (size_t)(w * 16 + lm) * PSTRIDE + tb * 16 + quad * 4) = pk;
    }
    ps += __shfl_xor(ps, 16, 64);
    ps += __shfl_xor(ps, 32, 64);
    l_i = l_i * alpha + ps;

    // rescale Oacc: alpha lives per m=lm; O rows are quad*4+r -> shuffle
    float af4[4];
#pragma unroll
    for (int r = 0; r < 4; ++r) af4[r] = __shfl(alpha, quad * 4 + r, 64);
#pragma unroll
    for (int jo = 0; jo < 4; ++jo)
#pragma unroll
      for (int r = 0; r < 4; ++r) Oacc[jo][r] *= af4[r];

    // O += P V  (wave-private Ps rows; lgkmcnt orders write->read in-wave)
#pragma unroll
    for (int kc = 0; kc < 2; ++kc) {
      bf16x8 ap = *(const bf16x8*)(Ps + (size_t)(w * 16 + lm) * PSTRIDE + kc * 32 + quad * 8);
      bf16x8 bv[4];
#pragma unroll
      for (int jo = 0; jo < 4; ++jo)
        bv[jo] = *(const bf16x8*)(Vs[cur] + (size_t)(((kc * 4 + quad) * 64 + jo * 16 + lm)) * 8);
#pragma unroll
      for (int jo = 0; jo < 4; ++jo)
        Oacc[jo] = __builtin_amdgcn_mfma_f32_16x16x32_bf16(ap, bv[jo], Oacc[jo], 0, 0, 0);
    }
  }

  // epilogue: normalize, write o_bf (b, s, h*64+d)
  float lf[4];
#pragma unroll
  for (int r = 0; r < 4; ++r) lf[r] = 1.0f / __shfl(l_i, quad * 4 + r, 64);
  const int b = bh >> 4, h = bh & 15;
#pragma unroll
  for (int jo = 0; jo < 4; ++jo)
#pragma unroll
    for (int r = 0; r < 4; ++r) {
      const int s   = qb * 128 + w * 16 + quad * 4 + r;
      const int col = h * 64 + jo * 16 + lm;
      O[((size_t)b * 2048 + s) * 1024 + col] = f2b(Oacc[jo][r] * lf[r]);
    }
}

// ---------------- output projection GEMM ----------------
// out[4096,1024] = Obf[4096,1024] @ Wo[1024,1024]^T + bias (fp32 out).
// 64x128 tiles, BK=32 dbuf; XCD rectangle 16m x 4n (3MB set).
__global__ __launch_bounds__(256) void oproj_gemm_kernel(
    const unsigned short* __restrict__ A,    // o_bf [4096][1024]
    const unsigned short* __restrict__ W,    // wo_bf [1024][1024]
    const float* __restrict__ bias,
    float* __restrict__ out)
{
  __shared__ unsigned short As[2][64 * 32];  // 4 KB x2
  __shared__ unsigned short Bs[2][128 * 32]; // 8 KB x2
  const int tid = threadIdx.x;
  const int w = tid >> 6, l = tid & 63;
  const int lm = l & 15, quad = l >> 4;
  const int g = blockIdx.x;                  // 0..511
  const int xcd = g & 7, t = g >> 3;         // t: 0..63
  const int m0 = ((xcd >> 1) * 16 + (t & 15)) * 64;
  const int n0 = ((xcd & 1) * 4 + (t >> 4)) * 128;

  const f32x4 fzero = {0.f, 0.f, 0.f, 0.f};
  f32x4 acc[4][2];
#pragma unroll
  for (int i = 0; i < 4; ++i)
#pragma unroll
    for (int j = 0; j < 2; ++j) acc[i][j] = fzero;

  const int rowS = w * 16 + lm;
  const unsigned short* ga  = A + (size_t)(m0 + rowS) * 1024 + quad * 8;
  const unsigned short* gb0 = W + (size_t)(n0 + rowS) * 1024 + quad * 8;
  const unsigned short* gb1 = W + (size_t)(n0 + rowS + 64) * 1024 + quad * 8;
  const size_t da = (size_t)(w * 64) * 8;
  const size_t db0 = da, db1 = (size_t)((w + 4) * 64) * 8;

  async16(ga,  As[0] + da);
  async16(gb0, Bs[0] + db0);
  async16(gb1, Bs[0] + db1);

  for (int it = 0; it < 32; ++it) {
    __syncthreads();
    const int cur = it & 1;
    if (it < 31) {
      const int k0 = (it + 1) * 32;
      async16(ga + k0,  As[cur ^ 1] + da);
      async16(gb0 + k0, Bs[cur ^ 1] + db0);
      async16(gb1 + k0, Bs[cur ^ 1] + db1);
    }
    bf16x8 af[4], bfc[2];
#pragma unroll
    for (int i = 0; i < 4; ++i)
      af[i] = *(const bf16x8*)(As[cur] + (size_t)((i * 64 + l)) * 8);
#pragma unroll
    for (int j = 0; j < 2; ++j)
      bfc[j] = *(const bf16x8*)(Bs[cur] + (size_t)(((w * 2 + j) * 64 + l)) * 8);
#pragma unroll
    for (int i = 0; i < 4; ++i)
#pragma unroll
      for (int j = 0; j < 2; ++j)
        acc[i][j] = __builtin_amdgcn_mfma_f32_16x16x32_bf16(af[i], bfc[j], acc[i][j], 0, 0, 0);
  }

#pragma unroll
  for (int i = 0; i < 4; ++i) {
#pragma unroll
    for (int j = 0; j < 2; ++j) {
      const int n = n0 + w * 32 + j * 16 + lm;
      const float bval = bias[n];
#pragma unroll
      for (int r = 0; r < 4; ++r) {
        const int m = m0 + i * 16 + quad * 4 + r;
        out[(size_t)m * 1024 + n] = acc[i][j][r] + bval;
      }
    }
  }
}

// ---------------- host launch ----------------
extern "C" void kernel_launch(void* const* d_in, const int* in_sizes, int n_in,
                              void* d_out, int out_size, void* d_ws, size_t ws_size,
                              hipStream_t stream) {
  (void)in_sizes; (void)n_in; (void)out_size; (void)ws_size;
  const float* x  = (const float*)d_in[0];
  const float* cp = (const float*)d_in[1];
  const float* sp = (const float*)d_in[2];
  const float* wq = (const float*)d_in[3];
  const float* bq = (const float*)d_in[4];
  const float* wk = (const float*)d_in[5];
  const float* bk = (const float*)d_in[6];
  const float* wv = (const float*)d_in[7];
  const float* bv = (const float*)d_in[8];
  const float* wo = (const float*)d_in[9];
  const float* bo = (const float*)d_in[10];
  float* out = (float*)d_out;

  unsigned short* xbf  = (unsigned short*)d_ws;          // 4M shorts
  unsigned short* wqkv = xbf  + (size_t)4 * 1024 * 1024; // 3M
  unsigned short* wobf = wqkv + (size_t)3 * 1024 * 1024; // 1M
  unsigned short* qbf  = wobf + (size_t)1 * 1024 * 1024; // 4M (bh,s,d)
  unsigned short* kbf  = qbf  + (size_t)4 * 1024 * 1024; // 4M (tiled frag-major)
  unsigned short* vbf  = kbf  + (size_t)4 * 1024 * 1024; // 4M (V^T tiled)
  unsigned short* obf  = vbf  + (size_t)4 * 1024 * 1024; // 4M (b,s,h*64+d)

  hipLaunchKernelGGL(cast_all_kernel, dim3(8192), dim3(256), 0, stream,
                     x, wq, wk, wv, wo, xbf, wqkv, wobf);

  hipLaunchKernelGGL(qkv_gemm_kernel, dim3(768), dim3(256), 0, stream,
                     xbf, wqkv, bq, bk, bv, cp, sp, qbf, kbf, vbf);
  hipLaunchKernelGGL(flash_kernel, dim3(32, 16), dim3(512), 0, stream,
                     qbf, kbf, vbf, obf);
  hipLaunchKernelGGL(oproj_gemm_kernel, dim3(512), dim3(256), 0, stream,
                     obf, wobf, bo, out);
}